// Round 4
// baseline (394.184 us; speedup 1.0000x reference)
//
#include <hip/hip_runtime.h>
#include <math.h>
#include <stdint.h>

constexpr int kB = 4;
constexpr int kS = 2048;
constexpr int kD = 1024;
constexpr int kH = 16;
constexpr int kHD = 64;

typedef __bf16 bf16;
typedef __attribute__((ext_vector_type(4))) __bf16 bf16x4;
typedef __attribute__((ext_vector_type(8))) __bf16 bf16x8;
typedef __attribute__((ext_vector_type(4))) float f32x4;

__device__ __forceinline__ f32x4 mfma16x16x32(bf16x8 a, bf16x8 b, f32x4 c) {
    return __builtin_amdgcn_mfma_f32_16x16x32_bf16(a, b, c, 0, 0, 0);
}

#if __has_builtin(__builtin_amdgcn_exp2f)
#define EXP2F(x) __builtin_amdgcn_exp2f(x)
#else
#define EXP2F(x) exp2f(x)
#endif

// async 16B global->LDS. lds base must be wave-uniform; HW adds lane*16.
__device__ __forceinline__ void load_lds16(const bf16* g, bf16* lds) {
    __builtin_amdgcn_global_load_lds(
        (const __attribute__((address_space(1))) void*)g,
        (__attribute__((address_space(3))) void*)lds, 16, 0, 0);
}

// ---------------------------------------------------------------------------
// prep_x: fp32 -> bf16 convert of x (8192x1024).
// ---------------------------------------------------------------------------
__global__ __launch_bounds__(256) void prep_x(const float* __restrict__ x,
                                              bf16* __restrict__ xb) {
    size_t i = ((size_t)blockIdx.x * 256 + threadIdx.x) * 8;
    float4 f0 = *(const float4*)(x + i);
    float4 f1 = *(const float4*)(x + i + 4);
    bf16x8 v;
    v[0] = (bf16)f0.x; v[1] = (bf16)f0.y; v[2] = (bf16)f0.z; v[3] = (bf16)f0.w;
    v[4] = (bf16)f1.x; v[5] = (bf16)f1.y; v[6] = (bf16)f1.z; v[7] = (bf16)f1.w;
    *(bf16x8*)(xb + i) = v;
}

// ---------------------------------------------------------------------------
// prep_w: Wt[z*1024 + n][k] = W_z[k][n] * scale_z (bf16, transposed)
// z=0 Wq scaled by 0.125*log2(e) (exp2-domain softmax), 1=Wk, 2=Wv, 3=Wo.
// ---------------------------------------------------------------------------
__global__ __launch_bounds__(256) void prep_w(const float* __restrict__ Wq,
                                              const float* __restrict__ Wk,
                                              const float* __restrict__ Wv,
                                              const float* __restrict__ Wo,
                                              bf16* __restrict__ Wt) {
    __shared__ bf16 t[64 * 72];
    const int z = blockIdx.z;
    const float* W = (z == 0) ? Wq : (z == 1) ? Wk : (z == 2) ? Wv : Wo;
    const float scale = (z == 0) ? 0.18033688011112042f : 1.0f;
    const int k0 = blockIdx.x * 64, n0 = blockIdx.y * 64;
    const int tid = threadIdx.x;
    for (int p = 0; p < 16; ++p) {
        int idx = tid + p * 256;
        int r = idx >> 6, c = idx & 63;
        t[r * 72 + c] = (bf16)(W[(size_t)(k0 + r) * kD + n0 + c] * scale);
    }
    __syncthreads();
    for (int p = 0; p < 16; ++p) {
        int idx = tid + p * 256;
        int r = idx >> 6, c = idx & 63;
        Wt[(size_t)(z * 1024 + n0 + r) * kD + k0 + c] = t[c * 72 + r];
    }
}

// ---------------------------------------------------------------------------
// qkv_gemm: m97 structure. 128x128 tile, BK=64, unpadded LDS, staged via
// global_load_lds width=16.  4 waves 2x2, each 64x64.
// Q,K -> [B,H,S,HD]; V -> transposed [B,H,HD,S].
// ---------------------------------------------------------------------------
__global__ __launch_bounds__(256) void qkv_gemm(
    const bf16* __restrict__ xb, const bf16* __restrict__ Wt,
    bf16* __restrict__ qo, bf16* __restrict__ ko, bf16* __restrict__ vto)
{
    __shared__ bf16 As[128 * 64];
    __shared__ bf16 Bs[128 * 64];

    const int tid  = threadIdx.x;
    const int wave = tid >> 6;
    const int lane = tid & 63;
    const int quad = lane >> 4;
    const int lr   = lane & 15;
    const int wm   = wave >> 1, wn = wave & 1;

    const int m0 = blockIdx.x * 128;
    const int n0 = blockIdx.y * 128;

    const int sr = tid >> 3, sc = tid & 7;

    f32x4 acc[4][4];
#pragma unroll
    for (int i = 0; i < 4; ++i)
#pragma unroll
        for (int nt = 0; nt < 4; ++nt) acc[i][nt] = f32x4{0.f, 0.f, 0.f, 0.f};

    for (int k0 = 0; k0 < kD; k0 += 64) {
        __syncthreads();
#pragma unroll
        for (int p = 0; p < 4; ++p) {
            int r = p * 32 + sr;
            load_lds16(&xb[(size_t)(m0 + r) * kD + k0 + sc * 8],
                       &As[(p * 256 + wave * 64) * 8]);
            load_lds16(&Wt[(size_t)(n0 + r) * kD + k0 + sc * 8],
                       &Bs[(p * 256 + wave * 64) * 8]);
        }
        __syncthreads();
#pragma unroll
        for (int kk = 0; kk < 2; ++kk) {
            bf16x8 a[4], b[4];
#pragma unroll
            for (int i = 0; i < 4; ++i)
                a[i] = *(const bf16x8*)&As[(wm * 64 + i * 16 + lr) * 64 + kk * 32 + quad * 8];
#pragma unroll
            for (int nt = 0; nt < 4; ++nt)
                b[nt] = *(const bf16x8*)&Bs[(wn * 64 + nt * 16 + lr) * 64 + kk * 32 + quad * 8];
#pragma unroll
            for (int i = 0; i < 4; ++i)
#pragma unroll
                for (int nt = 0; nt < 4; ++nt)
                    acc[i][nt] = mfma16x16x32(a[i], b[nt], acc[i][nt]);
        }
    }

    const int w_idx = n0 >> 10;               // 0=Q,1=K,2=V (uniform per block)
    if (w_idx < 2) {
        bf16* dst = (w_idx == 0) ? qo : ko;   // [B,H,S,HD]
#pragma unroll
        for (int i = 0; i < 4; ++i)
#pragma unroll
            for (int nt = 0; nt < 4; ++nt) {
                int n   = n0 + wn * 64 + nt * 16 + lr;
                int col = n & 1023, h = col >> 6, hd = col & 63;
#pragma unroll
                for (int j = 0; j < 4; ++j) {
                    int m = m0 + wm * 64 + i * 16 + quad * 4 + j;
                    int b = m >> 11, s = m & 2047;
                    dst[((size_t)(b * kH + h) * kS + s) * kHD + hd] = (bf16)acc[i][nt][j];
                }
            }
    } else {
        // V transposed: [B,H,HD,S]; j walks s -> bf16x4 stores
#pragma unroll
        for (int i = 0; i < 4; ++i)
#pragma unroll
            for (int nt = 0; nt < 4; ++nt) {
                int n   = n0 + wn * 64 + nt * 16 + lr;
                int col = n & 1023, h = col >> 6, hd = col & 63;
                int mb  = m0 + wm * 64 + i * 16 + quad * 4;
                int b = mb >> 11, s = mb & 2047;
                bf16x4 pk;
#pragma unroll
                for (int j = 0; j < 4; ++j) pk[j] = (bf16)acc[i][nt][j];
                *(bf16x4*)&vto[((size_t)(b * kH + h) * kHD + hd) * kS + s] = pk;
            }
    }
}

// ---------------------------------------------------------------------------
// attn v4: k-split causal attention.  One block (4 waves) per 32-row q-tile;
// wave w handles k-tiles w, w+4, w+8, ...  Unnormalized exp2-domain softmax
// makes the split associative: partial (O, l) just add.  End-of-block LDS
// reduction merges the 4 partials.  No cross-lane ops, no barriers in the
// k-loop.  Grid (S/32, B*H), bh-major with heavy q-tiles first per bh.
// ---------------------------------------------------------------------------
__global__ __launch_bounds__(256) void attn(
    const bf16* __restrict__ q, const bf16* __restrict__ k,
    const bf16* __restrict__ vt, bf16* __restrict__ ctx)
{
    // union: per-wave P buffers (k-loop) / fp32 reduction buffers (epilogue)
    __shared__ __align__(16) char smem[4 * 9216 + 512];

    const int tid  = threadIdx.x;
    const int wave = tid >> 6;
    const int lane = tid & 63;
    const int quad = lane >> 4;
    const int lr   = lane & 15;

    const int qt = (int)gridDim.x - 1 - (int)blockIdx.x;  // heavy tiles first
    const int bh = blockIdx.y;

    const bf16* qb_p = q  + (size_t)bh * kS * kHD;
    const bf16* kb_p = k  + (size_t)bh * kS * kHD;
    const bf16* vt_p = vt + (size_t)bh * kHD * kS; // [hd][s]

    const int base = qt * 32;                      // first q-row of this block

    bf16x8 aq[2][2];
#pragma unroll
    for (int g = 0; g < 2; ++g)
#pragma unroll
        for (int kk = 0; kk < 2; ++kk)
            aq[g][kk] = *(const bf16x8*)&qb_p[(size_t)(base + g * 16 + lr) * kHD + kk * 32 + quad * 8];

    f32x4 o[2][4];
    f32x4 lacc[2];
#pragma unroll
    for (int g = 0; g < 2; ++g) {
        lacc[g] = f32x4{0.f, 0.f, 0.f, 0.f};
#pragma unroll
        for (int nt = 0; nt < 4; ++nt) o[g][nt] = f32x4{0.f, 0.f, 0.f, 0.f};
    }

    bf16x8 ones;
#pragma unroll
    for (int i = 0; i < 8; ++i) ones[i] = (bf16)1.0f;

    const size_t koff = (size_t)lr * kHD + quad * 8;
    const size_t voff = (size_t)lr * kS + quad * 8;
    bf16* Pw = (bf16*)(smem + wave * 9216);        // 2 bufs x 32*72 bf16

    const int nkt = (base >> 6) + 1;
    for (int kt = wave; kt < nkt; kt += 4) {
        const int k0 = kt * 64;
        bf16* Pb = Pw + ((kt >> 2) & 1) * (32 * 72);

        bf16x8 kf[4][2], vf[4][2];
#pragma unroll
        for (int nt = 0; nt < 4; ++nt) {
            const bf16* kr = kb_p + koff + (size_t)k0 * kHD + nt * 1024;
            kf[nt][0] = *(const bf16x8*)kr;
            kf[nt][1] = *(const bf16x8*)(kr + 32);
            const bf16* vr = vt_p + voff + (size_t)nt * 16 * kS + k0;
            vf[nt][0] = *(const bf16x8*)vr;
            vf[nt][1] = *(const bf16x8*)(vr + 32);
        }

        const bool lastt = (kt == nkt - 1);
#pragma unroll
        for (int g = 0; g < 2; ++g) {
            f32x4 sg[4];
#pragma unroll
            for (int nt = 0; nt < 4; ++nt) {
                sg[nt] = mfma16x16x32(aq[g][0], kf[nt][0], f32x4{0.f, 0.f, 0.f, 0.f});
                sg[nt] = mfma16x16x32(aq[g][1], kf[nt][1], sg[nt]);
            }
            if (lastt) {
#pragma unroll
                for (int j = 0; j < 4; ++j) {
                    const int qg = base + g * 16 + quad * 4 + j;
#pragma unroll
                    for (int nt = 0; nt < 4; ++nt) {
                        float s = sg[nt][j];
                        s = (k0 + nt * 16 + lr > qg) ? -3.0e38f : s;
                        Pb[(g * 16 + quad * 4 + j) * 72 + nt * 16 + lr] = (bf16)EXP2F(s);
                    }
                }
            } else {
#pragma unroll
                for (int j = 0; j < 4; ++j)
#pragma unroll
                    for (int nt = 0; nt < 4; ++nt)
                        Pb[(g * 16 + quad * 4 + j) * 72 + nt * 16 + lr] = (bf16)EXP2F(sg[nt][j]);
            }
        }

        // O += P @ V ; l += P @ ones
#pragma unroll
        for (int g = 0; g < 2; ++g)
#pragma unroll
            for (int kk = 0; kk < 2; ++kk) {
                bf16x8 pa = *(const bf16x8*)&Pb[(g * 16 + lr) * 72 + kk * 32 + quad * 8];
                lacc[g] = mfma16x16x32(pa, ones, lacc[g]);
#pragma unroll
                for (int nt = 0; nt < 4; ++nt)
                    o[g][nt] = mfma16x16x32(pa, vf[nt][kk], o[g][nt]);
            }
    }

    // ---- cross-wave reduction: O_total = sum_w O_w, l_total = sum_w l_w ----
    __syncthreads();                       // all waves done with P buffers
    float* Obuf = (float*)smem;            // [4][32*64]
    float* lbuf = (float*)(smem + 4 * 8192);  // [4][32]
#pragma unroll
    for (int g = 0; g < 2; ++g)
#pragma unroll
        for (int nt = 0; nt < 4; ++nt)
#pragma unroll
            for (int j = 0; j < 4; ++j)
                Obuf[wave * 2048 + (g * 16 + quad * 4 + j) * 64 + nt * 16 + lr] = o[g][nt][j];
    if (lr == 0) {
#pragma unroll
        for (int g = 0; g < 2; ++g)
#pragma unroll
            for (int j = 0; j < 4; ++j)
                lbuf[wave * 32 + g * 16 + quad * 4 + j] = lacc[g][j];
    }
    __syncthreads();

    // wave w writes rows w*8 .. w*8+7; lane = column (h*64 + lane coalesced)
    const int b = bh >> 4;
    const int h = bh & 15;
#pragma unroll
    for (int r = 0; r < 8; ++r) {
        int row = wave * 8 + r;
        float s = Obuf[row * 64 + lane] + Obuf[2048 + row * 64 + lane] +
                  Obuf[4096 + row * 64 + lane] + Obuf[6144 + row * 64 + lane];
        float l = lbuf[row] + lbuf[32 + row] + lbuf[64 + row] + lbuf[96 + row];
        ctx[((size_t)(b * kS + base + row)) * kD + h * kHD + lane] = (bf16)(s / l);
    }
}

// ---------------------------------------------------------------------------
// out_gemm: out = ctx @ Wo + bo (fp32).  Same m97 structure.
// ---------------------------------------------------------------------------
__global__ __launch_bounds__(256) void out_gemm(
    const bf16* __restrict__ ctxb, const bf16* __restrict__ Wto,
    const float* __restrict__ bo, float* __restrict__ out)
{
    __shared__ bf16 As[128 * 64];
    __shared__ bf16 Bs[128 * 64];

    const int tid  = threadIdx.x;
    const int wave = tid >> 6;
    const int lane = tid & 63;
    const int quad = lane >> 4;
    const int lr   = lane & 15;
    const int wm   = wave >> 1, wn = wave & 1;

    const int m0 = blockIdx.x * 128;
    const int n0 = blockIdx.y * 128;

    const int sr = tid >> 3, sc = tid & 7;

    f32x4 acc[4][4];
#pragma unroll
    for (int i = 0; i < 4; ++i)
#pragma unroll
        for (int nt = 0; nt < 4; ++nt) acc[i][nt] = f32x4{0.f, 0.f, 0.f, 0.f};

    for (int k0 = 0; k0 < kD; k0 += 64) {
        __syncthreads();
#pragma unroll
        for (int p = 0; p < 4; ++p) {
            int r = p * 32 + sr;
            load_lds16(&ctxb[(size_t)(m0 + r) * kD + k0 + sc * 8],
                       &As[(p * 256 + wave * 64) * 8]);
            load_lds16(&Wto[(size_t)(n0 + r) * kD + k0 + sc * 8],
                       &Bs[(p * 256 + wave * 64) * 8]);
        }
        __syncthreads();
#pragma unroll
        for (int kk = 0; kk < 2; ++kk) {
            bf16x8 a[4], b[4];
#pragma unroll
            for (int i = 0; i < 4; ++i)
                a[i] = *(const bf16x8*)&As[(wm * 64 + i * 16 + lr) * 64 + kk * 32 + quad * 8];
#pragma unroll
            for (int nt = 0; nt < 4; ++nt)
                b[nt] = *(const bf16x8*)&Bs[(wn * 64 + nt * 16 + lr) * 64 + kk * 32 + quad * 8];
#pragma unroll
            for (int i = 0; i < 4; ++i)
#pragma unroll
                for (int nt = 0; nt < 4; ++nt)
                    acc[i][nt] = mfma16x16x32(a[i], b[nt], acc[i][nt]);
        }
    }

#pragma unroll
    for (int nt = 0; nt < 4; ++nt) {
        int n = n0 + wn * 64 + nt * 16 + lr;
        float bias = bo[n];
#pragma unroll
        for (int i = 0; i < 4; ++i)
#pragma unroll
            for (int j = 0; j < 4; ++j) {
                int m = m0 + wm * 64 + i * 16 + quad * 4 + j;
                out[(size_t)m * kD + n] = acc[i][nt][j] + bias;
            }
    }
}

// ---------------------------------------------------------------------------
extern "C" void kernel_launch(void* const* d_in, const int* in_sizes, int n_in,
                              void* d_out, int out_size, void* d_ws, size_t ws_size,
                              hipStream_t stream) {
    const float* x  = (const float*)d_in[0];
    const float* Wq = (const float*)d_in[1];
    const float* Wk = (const float*)d_in[2];
    const float* Wv = (const float*)d_in[3];
    const float* Wo = (const float*)d_in[4];
    const float* bo = (const float*)d_in[5];
    float* out = (float*)d_out;

    const size_t n_x   = (size_t)kB * kS * kD;       // 8,388,608
    const size_t n_w   = (size_t)4 * kD * kD;        // 4,194,304
    const size_t n_mat = (size_t)kB * kH * kS * kHD; // 8,388,608

    bf16* xb  = (bf16*)d_ws;        // 16 MB (reused as ctx after qkv_gemm)
    bf16* Wt  = xb + n_x;           // 8 MB
    bf16* Qm  = Wt + n_w;           // 16 MB [B,H,S,HD]
    bf16* Km  = Qm + n_mat;         // 16 MB [B,H,S,HD]
    bf16* Vt  = Km + n_mat;         // 16 MB [B,H,HD,S]
    bf16* ctx = xb;                 // reuse: x dead after qkv_gemm

    prep_x<<<dim3((int)(n_x / (256 * 8))), dim3(256), 0, stream>>>(x, xb);
    prep_w<<<dim3(16, 16, 4), dim3(256), 0, stream>>>(Wq, Wk, Wv, Wo, Wt);
    qkv_gemm<<<dim3(8192 / 128, 3072 / 128), dim3(256), 0, stream>>>(xb, Wt, Qm, Km, Vt);
    attn<<<dim3(kS / 32, kB * kH), dim3(256), 0, stream>>>(Qm, Km, Vt, ctx);
    out_gemm<<<dim3(8192 / 128, 1024 / 128), dim3(256), 0, stream>>>(
        ctx, Wt + (size_t)3 * kD * kD, bo, out);
}

// Round 5
// 362.080 us; speedup vs baseline: 1.0887x; 1.0887x over previous
//
#include <hip/hip_runtime.h>
#include <math.h>
#include <stdint.h>

constexpr int kB = 4;
constexpr int kS = 2048;
constexpr int kD = 1024;
constexpr int kH = 16;
constexpr int kHD = 64;

typedef __bf16 bf16;
typedef __attribute__((ext_vector_type(4))) __bf16 bf16x4;
typedef __attribute__((ext_vector_type(8))) __bf16 bf16x8;
typedef __attribute__((ext_vector_type(4))) float f32x4;

__device__ __forceinline__ f32x4 mfma16x16x32(bf16x8 a, bf16x8 b, f32x4 c) {
    return __builtin_amdgcn_mfma_f32_16x16x32_bf16(a, b, c, 0, 0, 0);
}

#if __has_builtin(__builtin_amdgcn_exp2f)
#define EXP2F(x) __builtin_amdgcn_exp2f(x)
#else
#define EXP2F(x) exp2f(x)
#endif

// async 16B global->LDS. lds base must be wave-uniform; HW adds lane*16.
__device__ __forceinline__ void load_lds16(const bf16* g, bf16* lds) {
    __builtin_amdgcn_global_load_lds(
        (const __attribute__((address_space(1))) void*)g,
        (__attribute__((address_space(3))) void*)lds, 16, 0, 0);
}

// ---------------------------------------------------------------------------
// prep_x: fp32 -> bf16 convert of x (8192x1024).
// ---------------------------------------------------------------------------
__global__ __launch_bounds__(256) void prep_x(const float* __restrict__ x,
                                              bf16* __restrict__ xb) {
    size_t i = ((size_t)blockIdx.x * 256 + threadIdx.x) * 8;
    float4 f0 = *(const float4*)(x + i);
    float4 f1 = *(const float4*)(x + i + 4);
    bf16x8 v;
    v[0] = (bf16)f0.x; v[1] = (bf16)f0.y; v[2] = (bf16)f0.z; v[3] = (bf16)f0.w;
    v[4] = (bf16)f1.x; v[5] = (bf16)f1.y; v[6] = (bf16)f1.z; v[7] = (bf16)f1.w;
    *(bf16x8*)(xb + i) = v;
}

// ---------------------------------------------------------------------------
// prep_w: Wt[z*1024 + n][k] = W_z[k][n] * scale_z (bf16, transposed)
// z=0 Wq scaled by 0.125*log2(e) (exp2-domain softmax), 1=Wk, 2=Wv, 3=Wo.
// ---------------------------------------------------------------------------
__global__ __launch_bounds__(256) void prep_w(const float* __restrict__ Wq,
                                              const float* __restrict__ Wk,
                                              const float* __restrict__ Wv,
                                              const float* __restrict__ Wo,
                                              bf16* __restrict__ Wt) {
    __shared__ bf16 t[64 * 72];
    const int z = blockIdx.z;
    const float* W = (z == 0) ? Wq : (z == 1) ? Wk : (z == 2) ? Wv : Wo;
    const float scale = (z == 0) ? 0.18033688011112042f : 1.0f;
    const int k0 = blockIdx.x * 64, n0 = blockIdx.y * 64;
    const int tid = threadIdx.x;
    for (int p = 0; p < 16; ++p) {
        int idx = tid + p * 256;
        int r = idx >> 6, c = idx & 63;
        t[r * 72 + c] = (bf16)(W[(size_t)(k0 + r) * kD + n0 + c] * scale);
    }
    __syncthreads();
    for (int p = 0; p < 16; ++p) {
        int idx = tid + p * 256;
        int r = idx >> 6, c = idx & 63;
        Wt[(size_t)(z * 1024 + n0 + r) * kD + k0 + c] = t[c * 72 + r];
    }
}

// ---------------------------------------------------------------------------
// qkv_gemm: m97 structure. 128x128 tile, BK=64, unpadded LDS, staged via
// global_load_lds width=16.  4 waves 2x2, each 64x64.
// Q,K -> [B,H,S,HD]; V -> transposed [B,H,HD,S].
// ---------------------------------------------------------------------------
__global__ __launch_bounds__(256) void qkv_gemm(
    const bf16* __restrict__ xb, const bf16* __restrict__ Wt,
    bf16* __restrict__ qo, bf16* __restrict__ ko, bf16* __restrict__ vto)
{
    __shared__ bf16 As[128 * 64];
    __shared__ bf16 Bs[128 * 64];

    const int tid  = threadIdx.x;
    const int wave = tid >> 6;
    const int lane = tid & 63;
    const int quad = lane >> 4;
    const int lr   = lane & 15;
    const int wm   = wave >> 1, wn = wave & 1;

    const int m0 = blockIdx.x * 128;
    const int n0 = blockIdx.y * 128;

    const int sr = tid >> 3, sc = tid & 7;

    f32x4 acc[4][4];
#pragma unroll
    for (int i = 0; i < 4; ++i)
#pragma unroll
        for (int nt = 0; nt < 4; ++nt) acc[i][nt] = f32x4{0.f, 0.f, 0.f, 0.f};

    for (int k0 = 0; k0 < kD; k0 += 64) {
        __syncthreads();
#pragma unroll
        for (int p = 0; p < 4; ++p) {
            int r = p * 32 + sr;
            load_lds16(&xb[(size_t)(m0 + r) * kD + k0 + sc * 8],
                       &As[(p * 256 + wave * 64) * 8]);
            load_lds16(&Wt[(size_t)(n0 + r) * kD + k0 + sc * 8],
                       &Bs[(p * 256 + wave * 64) * 8]);
        }
        __syncthreads();
#pragma unroll
        for (int kk = 0; kk < 2; ++kk) {
            bf16x8 a[4], b[4];
#pragma unroll
            for (int i = 0; i < 4; ++i)
                a[i] = *(const bf16x8*)&As[(wm * 64 + i * 16 + lr) * 64 + kk * 32 + quad * 8];
#pragma unroll
            for (int nt = 0; nt < 4; ++nt)
                b[nt] = *(const bf16x8*)&Bs[(wn * 64 + nt * 16 + lr) * 64 + kk * 32 + quad * 8];
#pragma unroll
            for (int i = 0; i < 4; ++i)
#pragma unroll
                for (int nt = 0; nt < 4; ++nt)
                    acc[i][nt] = mfma16x16x32(a[i], b[nt], acc[i][nt]);
        }
    }

    const int w_idx = n0 >> 10;               // 0=Q,1=K,2=V (uniform per block)
    if (w_idx < 2) {
        bf16* dst = (w_idx == 0) ? qo : ko;   // [B,H,S,HD]
#pragma unroll
        for (int i = 0; i < 4; ++i)
#pragma unroll
            for (int nt = 0; nt < 4; ++nt) {
                int n   = n0 + wn * 64 + nt * 16 + lr;
                int col = n & 1023, h = col >> 6, hd = col & 63;
#pragma unroll
                for (int j = 0; j < 4; ++j) {
                    int m = m0 + wm * 64 + i * 16 + quad * 4 + j;
                    int b = m >> 11, s = m & 2047;
                    dst[((size_t)(b * kH + h) * kS + s) * kHD + hd] = (bf16)acc[i][nt][j];
                }
            }
    } else {
        // V transposed: [B,H,HD,S]; j walks s -> bf16x4 stores
#pragma unroll
        for (int i = 0; i < 4; ++i)
#pragma unroll
            for (int nt = 0; nt < 4; ++nt) {
                int n   = n0 + wn * 64 + nt * 16 + lr;
                int col = n & 1023, h = col >> 6, hd = col & 63;
                int mb  = m0 + wm * 64 + i * 16 + quad * 4;
                int b = mb >> 11, s = mb & 2047;
                bf16x4 pk;
#pragma unroll
                for (int j = 0; j < 4; ++j) pk[j] = (bf16)acc[i][nt][j];
                *(bf16x4*)&vto[((size_t)(b * kH + h) * kHD + hd) * kS + s] = pk;
            }
    }
}

// ---------------------------------------------------------------------------
// attn v5 helpers
// ---------------------------------------------------------------------------
__device__ __forceinline__ void load_kv(const bf16* kr0, const bf16* vr0,
                                        bf16x8 (&kf)[4][2], bf16x8 (&vf)[4][2]) {
#pragma unroll
    for (int nt = 0; nt < 4; ++nt) {
        const bf16* kr = kr0 + nt * 1024;          // nt*16 rows * 64
        kf[nt][0] = *(const bf16x8*)kr;
        kf[nt][1] = *(const bf16x8*)(kr + 32);
        const bf16* vr = vr0 + (size_t)nt * 16 * kS;
        vf[nt][0] = *(const bf16x8*)vr;
        vf[nt][1] = *(const bf16x8*)(vr + 32);
    }
}

__device__ __forceinline__ void attn_tile(
    bf16x8 (&aq)[2][2], bf16x8 (&kf)[4][2], bf16x8 (&vf)[4][2],
    f32x4 (&o)[2][4], f32x4 (&lacc)[2], bf16* Pb, bf16x8 ones,
    int quad, int lr, int k0, int base, bool lastt)
{
#pragma unroll
    for (int g = 0; g < 2; ++g) {
        f32x4 sg[4];
#pragma unroll
        for (int nt = 0; nt < 4; ++nt) {
            sg[nt] = mfma16x16x32(aq[g][0], kf[nt][0], f32x4{0.f, 0.f, 0.f, 0.f});
            sg[nt] = mfma16x16x32(aq[g][1], kf[nt][1], sg[nt]);
        }
        if (lastt) {
#pragma unroll
            for (int j = 0; j < 4; ++j) {
                const int qg = base + g * 16 + quad * 4 + j;
#pragma unroll
                for (int nt = 0; nt < 4; ++nt) {
                    float s = sg[nt][j];
                    s = (k0 + nt * 16 + lr > qg) ? -3.0e38f : s;
                    Pb[(g * 16 + quad * 4 + j) * 72 + nt * 16 + lr] = (bf16)EXP2F(s);
                }
            }
        } else {
#pragma unroll
            for (int j = 0; j < 4; ++j)
#pragma unroll
                for (int nt = 0; nt < 4; ++nt)
                    Pb[(g * 16 + quad * 4 + j) * 72 + nt * 16 + lr] = (bf16)EXP2F(sg[nt][j]);
        }
    }
    // O += P @ V ; l += P @ ones   (same-wave DS ordering: writes before reads)
#pragma unroll
    for (int g = 0; g < 2; ++g)
#pragma unroll
        for (int kk = 0; kk < 2; ++kk) {
            bf16x8 pa = *(const bf16x8*)&Pb[(g * 16 + lr) * 72 + kk * 32 + quad * 8];
            lacc[g] = mfma16x16x32(pa, ones, lacc[g]);
#pragma unroll
            for (int nt = 0; nt < 4; ++nt)
                o[g][nt] = mfma16x16x32(pa, vf[nt][kk], o[g][nt]);
        }
}

// ---------------------------------------------------------------------------
// attn v5: register-double-buffer prefetched causal attention with
// heavy+light q-tile pairing.  Grid (16, B*H), block 128 (2 waves, 32 q-rows
// each).  Block handles 64-row q-tiles T=blockIdx.x and T'=31-blockIdx.x
// sequentially -> every wave does exactly 33 k-iterations (perfect balance,
// 2048 waves = 2/SIMD all-resident).  K/V frags for tile t+1 are loaded
// while tile t computes (no barriers anywhere in the loop).
// ---------------------------------------------------------------------------
__global__ __launch_bounds__(128, 2) void attn(
    const bf16* __restrict__ q, const bf16* __restrict__ k,
    const bf16* __restrict__ vt, bf16* __restrict__ ctx)
{
    __shared__ bf16 Pl[2][32 * 72];      // per-wave P (C-layout -> A-layout)

    const int tid  = threadIdx.x;
    const int wave = tid >> 6;
    const int lane = tid & 63;
    const int quad = lane >> 4;
    const int lr   = lane & 15;

    const int bh = blockIdx.y;

    const bf16* qb_p = q  + (size_t)bh * kS * kHD;
    const bf16* kb_p = k  + (size_t)bh * kS * kHD;
    const bf16* vt_p = vt + (size_t)bh * kHD * kS;   // [hd][s]

    bf16x8 ones;
#pragma unroll
    for (int i = 0; i < 8; ++i) ones[i] = (bf16)1.0f;

    const size_t koff = (size_t)lr * kHD + quad * 8;
    const size_t voff = (size_t)lr * kS + quad * 8;
    bf16* Pb = &Pl[wave][0];

    const int b = bh >> 4;
    const int h = bh & 15;

    const int pairT[2] = { (int)blockIdx.x, 31 - (int)blockIdx.x };

#pragma unroll 1
    for (int seg = 0; seg < 2; ++seg) {
        const int T    = pairT[seg];
        const int base = T * 64 + wave * 32;   // this wave's first q-row
        const int nkt  = T + 1;

        bf16x8 aq[2][2];
#pragma unroll
        for (int g = 0; g < 2; ++g)
#pragma unroll
            for (int kk = 0; kk < 2; ++kk)
                aq[g][kk] = *(const bf16x8*)&qb_p[(size_t)(base + g * 16 + lr) * kHD + kk * 32 + quad * 8];

        f32x4 o[2][4];
        f32x4 lacc[2];
#pragma unroll
        for (int g = 0; g < 2; ++g) {
            lacc[g] = f32x4{0.f, 0.f, 0.f, 0.f};
#pragma unroll
            for (int nt = 0; nt < 4; ++nt) o[g][nt] = f32x4{0.f, 0.f, 0.f, 0.f};
        }

        bf16x8 kfA[4][2], vfA[4][2], kfB[4][2], vfB[4][2];
        load_kv(kb_p + koff, vt_p + voff, kfA, vfA);   // tile 0

        int kt = 0;
        for (;;) {
            if (kt + 1 < nkt)
                load_kv(kb_p + koff + (size_t)(kt + 1) * 64 * kHD,
                        vt_p + voff + (kt + 1) * 64, kfB, vfB);
            attn_tile(aq, kfA, vfA, o, lacc, Pb, ones, quad, lr,
                      kt * 64, base, kt == nkt - 1);
            ++kt; if (kt == nkt) break;

            if (kt + 1 < nkt)
                load_kv(kb_p + koff + (size_t)(kt + 1) * 64 * kHD,
                        vt_p + voff + (kt + 1) * 64, kfA, vfA);
            attn_tile(aq, kfB, vfB, o, lacc, Pb, ones, quad, lr,
                      kt * 64, base, kt == nkt - 1);
            ++kt; if (kt == nkt) break;
        }

        // ctx [B,S,D] bf16, column h*64+hd
#pragma unroll
        for (int g = 0; g < 2; ++g) {
            float inv[4];
#pragma unroll
            for (int j = 0; j < 4; ++j) inv[j] = 1.0f / lacc[g][j];
#pragma unroll
            for (int nt = 0; nt < 4; ++nt) {
                int hd = nt * 16 + lr;
#pragma unroll
                for (int j = 0; j < 4; ++j) {
                    int qg = base + g * 16 + quad * 4 + j;
                    ctx[((size_t)(b * kS + qg)) * kD + h * kHD + hd] =
                        (bf16)(o[g][nt][j] * inv[j]);
                }
            }
        }
    }
}

// ---------------------------------------------------------------------------
// out_gemm: out = ctx @ Wo + bo (fp32).  Same m97 structure.
// ---------------------------------------------------------------------------
__global__ __launch_bounds__(256) void out_gemm(
    const bf16* __restrict__ ctxb, const bf16* __restrict__ Wto,
    const float* __restrict__ bo, float* __restrict__ out)
{
    __shared__ bf16 As[128 * 64];
    __shared__ bf16 Bs[128 * 64];

    const int tid  = threadIdx.x;
    const int wave = tid >> 6;
    const int lane = tid & 63;
    const int quad = lane >> 4;
    const int lr   = lane & 15;
    const int wm   = wave >> 1, wn = wave & 1;

    const int m0 = blockIdx.x * 128;
    const int n0 = blockIdx.y * 128;

    const int sr = tid >> 3, sc = tid & 7;

    f32x4 acc[4][4];
#pragma unroll
    for (int i = 0; i < 4; ++i)
#pragma unroll
        for (int nt = 0; nt < 4; ++nt) acc[i][nt] = f32x4{0.f, 0.f, 0.f, 0.f};

    for (int k0 = 0; k0 < kD; k0 += 64) {
        __syncthreads();
#pragma unroll
        for (int p = 0; p < 4; ++p) {
            int r = p * 32 + sr;
            load_lds16(&ctxb[(size_t)(m0 + r) * kD + k0 + sc * 8],
                       &As[(p * 256 + wave * 64) * 8]);
            load_lds16(&Wto[(size_t)(n0 + r) * kD + k0 + sc * 8],
                       &Bs[(p * 256 + wave * 64) * 8]);
        }
        __syncthreads();
#pragma unroll
        for (int kk = 0; kk < 2; ++kk) {
            bf16x8 a[4], b[4];
#pragma unroll
            for (int i = 0; i < 4; ++i)
                a[i] = *(const bf16x8*)&As[(wm * 64 + i * 16 + lr) * 64 + kk * 32 + quad * 8];
#pragma unroll
            for (int nt = 0; nt < 4; ++nt)
                b[nt] = *(const bf16x8*)&Bs[(wn * 64 + nt * 16 + lr) * 64 + kk * 32 + quad * 8];
#pragma unroll
            for (int i = 0; i < 4; ++i)
#pragma unroll
                for (int nt = 0; nt < 4; ++nt)
                    acc[i][nt] = mfma16x16x32(a[i], b[nt], acc[i][nt]);
        }
    }

#pragma unroll
    for (int nt = 0; nt < 4; ++nt) {
        int n = n0 + wn * 64 + nt * 16 + lr;
        float bias = bo[n];
#pragma unroll
        for (int i = 0; i < 4; ++i)
#pragma unroll
            for (int j = 0; j < 4; ++j) {
                int m = m0 + wm * 64 + i * 16 + quad * 4 + j;
                out[(size_t)m * kD + n] = acc[i][nt][j] + bias;
            }
    }
}

// ---------------------------------------------------------------------------
extern "C" void kernel_launch(void* const* d_in, const int* in_sizes, int n_in,
                              void* d_out, int out_size, void* d_ws, size_t ws_size,
                              hipStream_t stream) {
    const float* x  = (const float*)d_in[0];
    const float* Wq = (const float*)d_in[1];
    const float* Wk = (const float*)d_in[2];
    const float* Wv = (const float*)d_in[3];
    const float* Wo = (const float*)d_in[4];
    const float* bo = (const float*)d_in[5];
    float* out = (float*)d_out;

    const size_t n_x   = (size_t)kB * kS * kD;       // 8,388,608
    const size_t n_w   = (size_t)4 * kD * kD;        // 4,194,304
    const size_t n_mat = (size_t)kB * kH * kS * kHD; // 8,388,608

    bf16* xb  = (bf16*)d_ws;        // 16 MB (reused as ctx after qkv_gemm)
    bf16* Wt  = xb + n_x;           // 8 MB
    bf16* Qm  = Wt + n_w;           // 16 MB [B,H,S,HD]
    bf16* Km  = Qm + n_mat;         // 16 MB [B,H,S,HD]
    bf16* Vt  = Km + n_mat;         // 16 MB [B,H,HD,S]
    bf16* ctx = xb;                 // reuse: x dead after qkv_gemm

    prep_x<<<dim3((int)(n_x / (256 * 8))), dim3(256), 0, stream>>>(x, xb);
    prep_w<<<dim3(16, 16, 4), dim3(256), 0, stream>>>(Wq, Wk, Wv, Wo, Wt);
    qkv_gemm<<<dim3(8192 / 128, 3072 / 128), dim3(256), 0, stream>>>(xb, Wt, Qm, Km, Vt);
    attn<<<dim3(16, kB * kH), dim3(128), 0, stream>>>(Qm, Km, Vt, ctx);
    out_gemm<<<dim3(8192 / 128, 1024 / 128), dim3(256), 0, stream>>>(
        ctx, Wt + (size_t)3 * kD * kD, bo, out);
}

// Round 6
// 332.092 us; speedup vs baseline: 1.1870x; 1.0903x over previous
//
#include <hip/hip_runtime.h>
#include <math.h>
#include <stdint.h>

constexpr int kB = 4;
constexpr int kS = 2048;
constexpr int kD = 1024;
constexpr int kH = 16;
constexpr int kHD = 64;

typedef __bf16 bf16;
typedef __attribute__((ext_vector_type(4))) __bf16 bf16x4;
typedef __attribute__((ext_vector_type(8))) __bf16 bf16x8;
typedef __attribute__((ext_vector_type(4))) float f32x4;

__device__ __forceinline__ f32x4 mfma16x16x32(bf16x8 a, bf16x8 b, f32x4 c) {
    return __builtin_amdgcn_mfma_f32_16x16x32_bf16(a, b, c, 0, 0, 0);
}

#if __has_builtin(__builtin_amdgcn_exp2f)
#define EXP2F(x) __builtin_amdgcn_exp2f(x)
#else
#define EXP2F(x) exp2f(x)
#endif

// async 16B global->LDS. lds base must be wave-uniform; HW adds lane*16.
__device__ __forceinline__ void load_lds16(const bf16* g, bf16* lds) {
    __builtin_amdgcn_global_load_lds(
        (const __attribute__((address_space(1))) void*)g,
        (__attribute__((address_space(3))) void*)lds, 16, 0, 0);
}

// ---------------------------------------------------------------------------
// prep_x: fp32 -> bf16 convert of x (8192x1024).
// ---------------------------------------------------------------------------
__global__ __launch_bounds__(256) void prep_x(const float* __restrict__ x,
                                              bf16* __restrict__ xb) {
    size_t i = ((size_t)blockIdx.x * 256 + threadIdx.x) * 8;
    float4 f0 = *(const float4*)(x + i);
    float4 f1 = *(const float4*)(x + i + 4);
    bf16x8 v;
    v[0] = (bf16)f0.x; v[1] = (bf16)f0.y; v[2] = (bf16)f0.z; v[3] = (bf16)f0.w;
    v[4] = (bf16)f1.x; v[5] = (bf16)f1.y; v[6] = (bf16)f1.z; v[7] = (bf16)f1.w;
    *(bf16x8*)(xb + i) = v;
}

// ---------------------------------------------------------------------------
// prep_w: Wt[z*1024 + n][k] = W_z[k][n] * scale_z (bf16, transposed)
// z=0 Wq scaled by 0.125*log2(e) (exp2-domain softmax), 1=Wk, 2=Wv, 3=Wo.
// ---------------------------------------------------------------------------
__global__ __launch_bounds__(256) void prep_w(const float* __restrict__ Wq,
                                              const float* __restrict__ Wk,
                                              const float* __restrict__ Wv,
                                              const float* __restrict__ Wo,
                                              bf16* __restrict__ Wt) {
    __shared__ bf16 t[64 * 72];
    const int z = blockIdx.z;
    const float* W = (z == 0) ? Wq : (z == 1) ? Wk : (z == 2) ? Wv : Wo;
    const float scale = (z == 0) ? 0.18033688011112042f : 1.0f;
    const int k0 = blockIdx.x * 64, n0 = blockIdx.y * 64;
    const int tid = threadIdx.x;
    for (int p = 0; p < 16; ++p) {
        int idx = tid + p * 256;
        int r = idx >> 6, c = idx & 63;
        t[r * 72 + c] = (bf16)(W[(size_t)(k0 + r) * kD + n0 + c] * scale);
    }
    __syncthreads();
    for (int p = 0; p < 16; ++p) {
        int idx = tid + p * 256;
        int r = idx >> 6, c = idx & 63;
        Wt[(size_t)(z * 1024 + n0 + r) * kD + k0 + c] = t[c * 72 + r];
    }
}

// ---------------------------------------------------------------------------
// qkv_gemm: m97 structure. 128x128 tile, BK=64, unpadded LDS, staged via
// global_load_lds width=16.  4 waves 2x2, each 64x64.
// Q,K -> [B,H,S,HD]; V -> transposed [B,H,HD,S].
// ---------------------------------------------------------------------------
__global__ __launch_bounds__(256) void qkv_gemm(
    const bf16* __restrict__ xb, const bf16* __restrict__ Wt,
    bf16* __restrict__ qo, bf16* __restrict__ ko, bf16* __restrict__ vto)
{
    __shared__ bf16 As[128 * 64];
    __shared__ bf16 Bs[128 * 64];

    const int tid  = threadIdx.x;
    const int wave = tid >> 6;
    const int lane = tid & 63;
    const int quad = lane >> 4;
    const int lr   = lane & 15;
    const int wm   = wave >> 1, wn = wave & 1;

    const int m0 = blockIdx.x * 128;
    const int n0 = blockIdx.y * 128;

    const int sr = tid >> 3, sc = tid & 7;

    f32x4 acc[4][4];
#pragma unroll
    for (int i = 0; i < 4; ++i)
#pragma unroll
        for (int nt = 0; nt < 4; ++nt) acc[i][nt] = f32x4{0.f, 0.f, 0.f, 0.f};

    for (int k0 = 0; k0 < kD; k0 += 64) {
        __syncthreads();
#pragma unroll
        for (int p = 0; p < 4; ++p) {
            int r = p * 32 + sr;
            load_lds16(&xb[(size_t)(m0 + r) * kD + k0 + sc * 8],
                       &As[(p * 256 + wave * 64) * 8]);
            load_lds16(&Wt[(size_t)(n0 + r) * kD + k0 + sc * 8],
                       &Bs[(p * 256 + wave * 64) * 8]);
        }
        __syncthreads();
#pragma unroll
        for (int kk = 0; kk < 2; ++kk) {
            bf16x8 a[4], b[4];
#pragma unroll
            for (int i = 0; i < 4; ++i)
                a[i] = *(const bf16x8*)&As[(wm * 64 + i * 16 + lr) * 64 + kk * 32 + quad * 8];
#pragma unroll
            for (int nt = 0; nt < 4; ++nt)
                b[nt] = *(const bf16x8*)&Bs[(wn * 64 + nt * 16 + lr) * 64 + kk * 32 + quad * 8];
#pragma unroll
            for (int i = 0; i < 4; ++i)
#pragma unroll
                for (int nt = 0; nt < 4; ++nt)
                    acc[i][nt] = mfma16x16x32(a[i], b[nt], acc[i][nt]);
        }
    }

    const int w_idx = n0 >> 10;               // 0=Q,1=K,2=V (uniform per block)
    if (w_idx < 2) {
        bf16* dst = (w_idx == 0) ? qo : ko;   // [B,H,S,HD]
#pragma unroll
        for (int i = 0; i < 4; ++i)
#pragma unroll
            for (int nt = 0; nt < 4; ++nt) {
                int n   = n0 + wn * 64 + nt * 16 + lr;
                int col = n & 1023, h = col >> 6, hd = col & 63;
#pragma unroll
                for (int j = 0; j < 4; ++j) {
                    int m = m0 + wm * 64 + i * 16 + quad * 4 + j;
                    int b = m >> 11, s = m & 2047;
                    dst[((size_t)(b * kH + h) * kS + s) * kHD + hd] = (bf16)acc[i][nt][j];
                }
            }
    } else {
        // V transposed: [B,H,HD,S]; j walks s -> bf16x4 stores
#pragma unroll
        for (int i = 0; i < 4; ++i)
#pragma unroll
            for (int nt = 0; nt < 4; ++nt) {
                int n   = n0 + wn * 64 + nt * 16 + lr;
                int col = n & 1023, h = col >> 6, hd = col & 63;
                int mb  = m0 + wm * 64 + i * 16 + quad * 4;
                int b = mb >> 11, s = mb & 2047;
                bf16x4 pk;
#pragma unroll
                for (int j = 0; j < 4; ++j) pk[j] = (bf16)acc[i][nt][j];
                *(bf16x4*)&vto[((size_t)(b * kH + h) * kHD + hd) * kS + s] = pk;
            }
    }
}

// ---------------------------------------------------------------------------
// attn helpers
// ---------------------------------------------------------------------------
__device__ __forceinline__ void load_kv(const bf16* kr0, const bf16* vr0,
                                        bf16x8 (&kf)[4][2], bf16x8 (&vf)[4][2]) {
#pragma unroll
    for (int nt = 0; nt < 4; ++nt) {
        const bf16* kr = kr0 + nt * 1024;          // nt*16 rows * 64
        kf[nt][0] = *(const bf16x8*)kr;
        kf[nt][1] = *(const bf16x8*)(kr + 32);
        const bf16* vr = vr0 + (size_t)nt * 16 * kS;
        vf[nt][0] = *(const bf16x8*)vr;
        vf[nt][1] = *(const bf16x8*)(vr + 32);
    }
}

__device__ __forceinline__ void attn_tile(
    bf16x8 (&aq)[2][2], bf16x8 (&kf)[4][2], bf16x8 (&vf)[4][2],
    f32x4 (&o)[2][4], f32x4 (&lacc)[2], bf16* Pb, bf16x8 ones,
    int quad, int lr, int k0, int base, bool lastt)
{
#pragma unroll
    for (int g = 0; g < 2; ++g) {
        f32x4 sg[4];
#pragma unroll
        for (int nt = 0; nt < 4; ++nt) {
            sg[nt] = mfma16x16x32(aq[g][0], kf[nt][0], f32x4{0.f, 0.f, 0.f, 0.f});
            sg[nt] = mfma16x16x32(aq[g][1], kf[nt][1], sg[nt]);
        }
        if (lastt) {
#pragma unroll
            for (int j = 0; j < 4; ++j) {
                const int qg = base + g * 16 + quad * 4 + j;
#pragma unroll
                for (int nt = 0; nt < 4; ++nt) {
                    float s = sg[nt][j];
                    s = (k0 + nt * 16 + lr > qg) ? -3.0e38f : s;
                    Pb[(g * 16 + quad * 4 + j) * 72 + nt * 16 + lr] = (bf16)EXP2F(s);
                }
            }
        } else {
#pragma unroll
            for (int j = 0; j < 4; ++j)
#pragma unroll
                for (int nt = 0; nt < 4; ++nt)
                    Pb[(g * 16 + quad * 4 + j) * 72 + nt * 16 + lr] = (bf16)EXP2F(sg[nt][j]);
        }
    }
    // O += P @ V ; l += P @ ones   (same-wave DS ordering: writes before reads)
#pragma unroll
    for (int g = 0; g < 2; ++g)
#pragma unroll
        for (int kk = 0; kk < 2; ++kk) {
            bf16x8 pa = *(const bf16x8*)&Pb[(g * 16 + lr) * 72 + kk * 32 + quad * 8];
            lacc[g] = mfma16x16x32(pa, ones, lacc[g]);
#pragma unroll
            for (int nt = 0; nt < 4; ++nt)
                o[g][nt] = mfma16x16x32(pa, vf[nt][kk], o[g][nt]);
        }
}

// ---------------------------------------------------------------------------
// attn v6: R3's lock-step all-resident grid + R5's register double-buffer
// prefetch.  Grid (B*H, S/64) with bh fastest and heavy q-tiles dispatched
// first; 2048 blocks x 2 waves, all resident, every block traverses
// kt=0,1,2,... in lock-step so each K/V tile is HBM-fetched once and
// L2-served to all sharers.  No barriers, no pairing.
// ---------------------------------------------------------------------------
__global__ __launch_bounds__(128, 2) void attn(
    const bf16* __restrict__ q, const bf16* __restrict__ k,
    const bf16* __restrict__ vt, bf16* __restrict__ ctx)
{
    __shared__ bf16 Pl[2][32 * 72];      // per-wave P (C-layout -> A-layout)

    const int tid  = threadIdx.x;
    const int wave = tid >> 6;
    const int lane = tid & 63;
    const int quad = lane >> 4;
    const int lr   = lane & 15;

    const int bh = blockIdx.x;
    const int qt = (int)gridDim.y - 1 - (int)blockIdx.y;   // heavy tiles first

    const bf16* qb_p = q  + (size_t)bh * kS * kHD;
    const bf16* kb_p = k  + (size_t)bh * kS * kHD;
    const bf16* vt_p = vt + (size_t)bh * kHD * kS;   // [hd][s]

    bf16x8 ones;
#pragma unroll
    for (int i = 0; i < 8; ++i) ones[i] = (bf16)1.0f;

    const size_t koff = (size_t)lr * kHD + quad * 8;
    const size_t voff = (size_t)lr * kS + quad * 8;
    bf16* Pb = &Pl[wave][0];

    const int base = qt * 64 + wave * 32;            // this wave's first q-row
    const int nkt  = qt + 1;

    bf16x8 aq[2][2];
#pragma unroll
    for (int g = 0; g < 2; ++g)
#pragma unroll
        for (int kk = 0; kk < 2; ++kk)
            aq[g][kk] = *(const bf16x8*)&qb_p[(size_t)(base + g * 16 + lr) * kHD + kk * 32 + quad * 8];

    f32x4 o[2][4];
    f32x4 lacc[2];
#pragma unroll
    for (int g = 0; g < 2; ++g) {
        lacc[g] = f32x4{0.f, 0.f, 0.f, 0.f};
#pragma unroll
        for (int nt = 0; nt < 4; ++nt) o[g][nt] = f32x4{0.f, 0.f, 0.f, 0.f};
    }

    bf16x8 kfA[4][2], vfA[4][2], kfB[4][2], vfB[4][2];
    load_kv(kb_p + koff, vt_p + voff, kfA, vfA);     // tile 0

    int kt = 0;
    for (;;) {
        if (kt + 1 < nkt)
            load_kv(kb_p + koff + (size_t)(kt + 1) * 64 * kHD,
                    vt_p + voff + (kt + 1) * 64, kfB, vfB);
        attn_tile(aq, kfA, vfA, o, lacc, Pb, ones, quad, lr,
                  kt * 64, base, kt == nkt - 1);
        ++kt; if (kt == nkt) break;

        if (kt + 1 < nkt)
            load_kv(kb_p + koff + (size_t)(kt + 1) * 64 * kHD,
                    vt_p + voff + (kt + 1) * 64, kfA, vfA);
        attn_tile(aq, kfB, vfB, o, lacc, Pb, ones, quad, lr,
                  kt * 64, base, kt == nkt - 1);
        ++kt; if (kt == nkt) break;
    }

    // ctx [B,S,D] bf16, column h*64+hd
    const int b = bh >> 4;
    const int h = bh & 15;
#pragma unroll
    for (int g = 0; g < 2; ++g) {
        float inv[4];
#pragma unroll
        for (int j = 0; j < 4; ++j) inv[j] = 1.0f / lacc[g][j];
#pragma unroll
        for (int nt = 0; nt < 4; ++nt) {
            int hd = nt * 16 + lr;
#pragma unroll
            for (int j = 0; j < 4; ++j) {
                int qg = base + g * 16 + quad * 4 + j;
                ctx[((size_t)(b * kS + qg)) * kD + h * kHD + hd] =
                    (bf16)(o[g][nt][j] * inv[j]);
            }
        }
    }
}

// ---------------------------------------------------------------------------
// out_gemm: out = ctx @ Wo + bo (fp32).  Same m97 structure.
// ---------------------------------------------------------------------------
__global__ __launch_bounds__(256) void out_gemm(
    const bf16* __restrict__ ctxb, const bf16* __restrict__ Wto,
    const float* __restrict__ bo, float* __restrict__ out)
{
    __shared__ bf16 As[128 * 64];
    __shared__ bf16 Bs[128 * 64];

    const int tid  = threadIdx.x;
    const int wave = tid >> 6;
    const int lane = tid & 63;
    const int quad = lane >> 4;
    const int lr   = lane & 15;
    const int wm   = wave >> 1, wn = wave & 1;

    const int m0 = blockIdx.x * 128;
    const int n0 = blockIdx.y * 128;

    const int sr = tid >> 3, sc = tid & 7;

    f32x4 acc[4][4];
#pragma unroll
    for (int i = 0; i < 4; ++i)
#pragma unroll
        for (int nt = 0; nt < 4; ++nt) acc[i][nt] = f32x4{0.f, 0.f, 0.f, 0.f};

    for (int k0 = 0; k0 < kD; k0 += 64) {
        __syncthreads();
#pragma unroll
        for (int p = 0; p < 4; ++p) {
            int r = p * 32 + sr;
            load_lds16(&ctxb[(size_t)(m0 + r) * kD + k0 + sc * 8],
                       &As[(p * 256 + wave * 64) * 8]);
            load_lds16(&Wto[(size_t)(n0 + r) * kD + k0 + sc * 8],
                       &Bs[(p * 256 + wave * 64) * 8]);
        }
        __syncthreads();
#pragma unroll
        for (int kk = 0; kk < 2; ++kk) {
            bf16x8 a[4], b[4];
#pragma unroll
            for (int i = 0; i < 4; ++i)
                a[i] = *(const bf16x8*)&As[(wm * 64 + i * 16 + lr) * 64 + kk * 32 + quad * 8];
#pragma unroll
            for (int nt = 0; nt < 4; ++nt)
                b[nt] = *(const bf16x8*)&Bs[(wn * 64 + nt * 16 + lr) * 64 + kk * 32 + quad * 8];
#pragma unroll
            for (int i = 0; i < 4; ++i)
#pragma unroll
                for (int nt = 0; nt < 4; ++nt)
                    acc[i][nt] = mfma16x16x32(a[i], b[nt], acc[i][nt]);
        }
    }

#pragma unroll
    for (int nt = 0; nt < 4; ++nt) {
        int n = n0 + wn * 64 + nt * 16 + lr;
        float bias = bo[n];
#pragma unroll
        for (int i = 0; i < 4; ++i)
#pragma unroll
            for (int j = 0; j < 4; ++j) {
                int m = m0 + wm * 64 + i * 16 + quad * 4 + j;
                out[(size_t)m * kD + n] = acc[i][nt][j] + bias;
            }
    }
}

// ---------------------------------------------------------------------------
extern "C" void kernel_launch(void* const* d_in, const int* in_sizes, int n_in,
                              void* d_out, int out_size, void* d_ws, size_t ws_size,
                              hipStream_t stream) {
    const float* x  = (const float*)d_in[0];
    const float* Wq = (const float*)d_in[1];
    const float* Wk = (const float*)d_in[2];
    const float* Wv = (const float*)d_in[3];
    const float* Wo = (const float*)d_in[4];
    const float* bo = (const float*)d_in[5];
    float* out = (float*)d_out;

    const size_t n_x   = (size_t)kB * kS * kD;       // 8,388,608
    const size_t n_w   = (size_t)4 * kD * kD;        // 4,194,304
    const size_t n_mat = (size_t)kB * kH * kS * kHD; // 8,388,608

    bf16* xb  = (bf16*)d_ws;        // 16 MB (reused as ctx after qkv_gemm)
    bf16* Wt  = xb + n_x;           // 8 MB
    bf16* Qm  = Wt + n_w;           // 16 MB [B,H,S,HD]
    bf16* Km  = Qm + n_mat;         // 16 MB [B,H,S,HD]
    bf16* Vt  = Km + n_mat;         // 16 MB [B,H,HD,S]
    bf16* ctx = xb;                 // reuse: x dead after qkv_gemm

    prep_x<<<dim3((int)(n_x / (256 * 8))), dim3(256), 0, stream>>>(x, xb);
    prep_w<<<dim3(16, 16, 4), dim3(256), 0, stream>>>(Wq, Wk, Wv, Wo, Wt);
    qkv_gemm<<<dim3(8192 / 128, 3072 / 128), dim3(256), 0, stream>>>(xb, Wt, Qm, Km, Vt);
    attn<<<dim3(kB * kH, kS / 64), dim3(128), 0, stream>>>(Qm, Km, Vt, ctx);
    out_gemm<<<dim3(8192 / 128, 1024 / 128), dim3(256), 0, stream>>>(
        ctx, Wt + (size_t)3 * kD * kD, bo, out);
}